// Round 6
// baseline (535.354 us; speedup 1.0000x reference)
//
#include <hip/hip_runtime.h>

#define NNODES 50000
#define HID 128
#define NREL 9
#define NLAYERS 3
#define NEDGES 600000

#define NBINS (NREL * NNODES)          // 450000, bin = r*NNODES + d  (r-major)
#define SCAN_CHUNK 1024
#define NBLK ((NBINS + SCAN_CHUNK - 1) / SCAN_CHUNK)   // 440

#define KTOT (NREL * HID)               // 1152
#define GM2 32                          // gemm M-tile -> 1563 blocks
#define FPITCH 136                      // gemm LDS pitch in shorts (272 B rows, 2-way banks = free)

// gather geometry: col-sliced for XCD L2 residency
#define GSLICES 4                       // 4 slices x 32 cols; slice s -> XCDs {s, s+4} (bid%8)
#define GCOLS 32                        // slice working set = 50000*32*2 B = 3.2 MB < 4 MB XCD L2
#define GROWS 64                        // rows per gather block
#define GTILES ((NNODES + GROWS - 1) / GROWS)   // 782

// prep_kernel block ranges
#define HIST_BLKS ((NEDGES + 255) / 256)            // 2344
#define EMB_BLKS  ((NNODES * HID / 8) / 256)        // 3125
#define W_BLKS    (NLAYERS * NREL)                  // 27

typedef __attribute__((ext_vector_type(8))) short short8;
typedef __attribute__((ext_vector_type(4))) float f32x4;

__device__ __forceinline__ short f2bf(float f) {
    union { float f; unsigned u; } c; c.f = f;
    unsigned r = c.u + 0x7fff + ((c.u >> 16) & 1);   // RNE
    return (short)(r >> 16);
}
__device__ __forceinline__ float bf2f(short v) {
    return __uint_as_float(((unsigned)(unsigned short)v) << 16);
}

// ---------------- prep: histogram + emb convert + W convert (one dispatch) ----------------
// Wt2[l][n][r*128+kk] = bf16(W[l][r][kk][n])   (r-major K)

__global__ __launch_bounds__(256) void prep_kernel(const int* __restrict__ dst,
                                                   const int* __restrict__ etype,
                                                   int* __restrict__ bins,
                                                   const float* __restrict__ E,
                                                   short* __restrict__ Ebf,
                                                   const float* __restrict__ W,
                                                   short* __restrict__ Wt2) {
    int b = blockIdx.x, tid = threadIdx.x;
    if (b < HIST_BLKS) {
        int e = b * 256 + tid;
        if (e < NEDGES) {
            int bin = etype[e] * NNODES + dst[e];
            atomicAdd(&bins[bin], 1);
        }
    } else if (b < HIST_BLKS + EMB_BLKS) {
        int gid = (b - HIST_BLKS) * 256 + tid;
        const float* p = E + (size_t)gid * 8;
        float4 v0 = *(const float4*)p;
        float4 v1 = *(const float4*)(p + 4);
        short8 o = {f2bf(v0.x), f2bf(v0.y), f2bf(v0.z), f2bf(v0.w),
                    f2bf(v1.x), f2bf(v1.y), f2bf(v1.z), f2bf(v1.w)};
        *(short8*)(Ebf + (size_t)gid * 8) = o;
    } else {
        int lr = b - HIST_BLKS - EMB_BLKS;
        int l = lr / NREL, r = lr - l * NREL;
        const float* w = W + (size_t)lr * HID * HID;
        short* o = Wt2 + (size_t)l * HID * KTOT;
#pragma unroll 4
        for (int i = 0; i < 64; i++) {
            int elem = i * 256 + tid;
            int kk = elem >> 7, n = elem & 127;
            o[(size_t)n * KTOT + r * HID + kk] = f2bf(w[elem]);
        }
    }
}

// ---------------- scans ----------------

__global__ __launch_bounds__(256) void scan_pass1(const int* __restrict__ bins,
                                                  int* __restrict__ blocksum) {
    __shared__ int red[256];
    int b = blockIdx.x, t = threadIdx.x;
    int i0 = b * SCAN_CHUNK + t * 4;
    int s = 0;
#pragma unroll
    for (int k = 0; k < 4; k++)
        if (i0 + k < NBINS) s += bins[i0 + k];
    red[t] = s;
    __syncthreads();
    for (int off = 128; off > 0; off >>= 1) {
        if (t < off) red[t] += red[t + off];
        __syncthreads();
    }
    if (t == 0) blocksum[b] = red[0];
}

__global__ __launch_bounds__(512) void scan_pass2(const int* __restrict__ blocksum,
                                                  int* __restrict__ blockoff,
                                                  int* __restrict__ rowptr) {
    __shared__ int s[512];
    int t = threadIdx.x;
    int v = (t < NBLK) ? blocksum[t] : 0;
    s[t] = v;
    __syncthreads();
    for (int off = 1; off < 512; off <<= 1) {
        int x = (t >= off) ? s[t - off] : 0;
        __syncthreads();
        s[t] += x;
        __syncthreads();
    }
    if (t < NBLK) blockoff[t] = s[t] - v;
    if (t == 0) rowptr[NBINS] = NEDGES;
}

__global__ __launch_bounds__(256) void scan_pass3(const int* __restrict__ bins,
                                                  const int* __restrict__ blockoff,
                                                  int* __restrict__ rowptr,
                                                  int* __restrict__ cursor) {
    __shared__ int sc[256];
    int b = blockIdx.x, t = threadIdx.x;
    int i0 = b * SCAN_CHUNK + t * 4;
    int v[4], p[4];
    int s = 0;
#pragma unroll
    for (int k = 0; k < 4; k++) {
        v[k] = (i0 + k < NBINS) ? bins[i0 + k] : 0;
        p[k] = s;
        s += v[k];
    }
    sc[t] = s;
    __syncthreads();
    for (int off = 1; off < 256; off <<= 1) {
        int x = (t >= off) ? sc[t - off] : 0;
        __syncthreads();
        sc[t] += x;
        __syncthreads();
    }
    int base = blockoff[b] + (sc[t] - s);
#pragma unroll
    for (int k = 0; k < 4; k++) {
        if (i0 + k < NBINS) {
            rowptr[i0 + k] = base + p[k];
            cursor[i0 + k] = base + p[k];
        }
    }
}

__global__ void place_kernel(const int* __restrict__ dst, const int* __restrict__ src,
                             const int* __restrict__ etype,
                             int* __restrict__ cursor, int* __restrict__ bsrc) {
    int e = blockIdx.x * blockDim.x + threadIdx.x;
    if (e < NEDGES) {
        int bin = etype[e] * NNODES + dst[e];
        int pos = atomicAdd(&cursor[bin], 1);
        bsrc[pos] = src[e];
    }
}

// ---------------- gather: col-sliced bin sums, S[d][r*128+c] = sum_{e in bin(d,r)} H[src_e][c] ----------------
// Grid: 782 tiles x 4 slices, bid = tile*4 + slice -> slice s maps to XCDs {s,s+4}
// (bid%8 round-robin), so each XCD's L2 caches only H[:, slice cols] = 3.2 MB.
// Thread = (row grow, 8-col lane lc); 4-wide masked edge groups (round-5 proven);
// next-relation idx prefetch; NO barriers in the main loop; register accumulation.
// Arithmetic order per bin identical to round 5 (passed): (a+m1*b)+(m2*c+m3*d) per col.

__global__ __launch_bounds__(256) void gather_kernel(const short* __restrict__ Hin,
                                                     const int* __restrict__ rowptr,
                                                     const int* __restrict__ bsrc,
                                                     short* __restrict__ S) {
    __shared__ int rp_s[NREL * (GROWS + 1)];      // 585 ints
    int bid = blockIdx.x;
    int slice = bid & (GSLICES - 1);
    int tile  = bid >> 2;
    int row0  = tile * GROWS;
    int tid   = threadIdx.x;
    int grow  = tid >> 2;          // 0..63 dest row
    int lc    = tid & 3;           // 8-col lane within the 32-col slice

    for (int i = tid; i < NREL * (GROWS + 1); i += 256) {
        int r = i / (GROWS + 1), o = i - r * (GROWS + 1);
        int d = row0 + o; if (d > NNODES) d = NNODES;   // clamp -> cnt 0 for pad rows
        rp_s[i] = rowptr[r * NNODES + d];
    }
    __syncthreads();

    const short* hb = Hin + slice * GCOLS + lc * 8;
    short*       sp = S + (size_t)(row0 + grow) * KTOT + slice * GCOLS + lc * 8;
    int active = (row0 + grow) < NNODES;

    // idx prefetch for relation 0 (bsrc +8 pad makes raw j..j+3 loads safe)
    int rs = rp_s[grow];
    int re = rp_s[grow + 1];
    int pf0 = 0, pf1 = 0, pf2 = 0, pf3 = 0;
    if (rs < re) { pf0 = bsrc[rs]; pf1 = bsrc[rs + 1]; pf2 = bsrc[rs + 2]; pf3 = bsrc[rs + 3]; }

    for (int r = 0; r < NREL; r++) {
        float ga[8];
#pragma unroll
        for (int i = 0; i < 8; i++) ga[i] = 0.f;

        int j = rs;
        if (j < re) {
            int rem = re - j;
            int s0 = pf0;
            int s1 = (rem > 1) ? pf1 : s0;
            int s2 = (rem > 2) ? pf2 : s0;
            int s3 = (rem > 3) ? pf3 : s0;
            short8 a = *(const short8*)(hb + (size_t)s0 * HID);
            short8 b = *(const short8*)(hb + (size_t)s1 * HID);
            short8 c = *(const short8*)(hb + (size_t)s2 * HID);
            short8 d = *(const short8*)(hb + (size_t)s3 * HID);
            float m1 = (rem > 1) ? 1.f : 0.f;
            float m2 = (rem > 2) ? 1.f : 0.f;
            float m3 = (rem > 3) ? 1.f : 0.f;
#pragma unroll
            for (int k = 0; k < 8; k++)
                ga[k] += (bf2f(a[k]) + m1 * bf2f(b[k])) + (m2 * bf2f(c[k]) + m3 * bf2f(d[k]));
            j += 4;
        }
        for (; j < re; j += 4) {       // rare long-bin path (>4 edges)
            int rem = re - j;
            int s0 = bsrc[j];
            int t1 = bsrc[j + 1];
            int t2 = bsrc[j + 2];
            int t3 = bsrc[j + 3];
            int s1 = (rem > 1) ? t1 : s0;
            int s2 = (rem > 2) ? t2 : s0;
            int s3 = (rem > 3) ? t3 : s0;
            short8 a = *(const short8*)(hb + (size_t)s0 * HID);
            short8 b = *(const short8*)(hb + (size_t)s1 * HID);
            short8 c = *(const short8*)(hb + (size_t)s2 * HID);
            short8 d = *(const short8*)(hb + (size_t)s3 * HID);
            float m1 = (rem > 1) ? 1.f : 0.f;
            float m2 = (rem > 2) ? 1.f : 0.f;
            float m3 = (rem > 3) ? 1.f : 0.f;
#pragma unroll
            for (int k = 0; k < 8; k++)
                ga[k] += (bf2f(a[k]) + m1 * bf2f(b[k])) + (m2 * bf2f(c[k]) + m3 * bf2f(d[k]));
        }

        // idx prefetch for next relation (resolves during this store + next accum)
        if (r + 1 < NREL) {
            rs = rp_s[(r + 1) * (GROWS + 1) + grow];
            re = rp_s[(r + 1) * (GROWS + 1) + grow + 1];
            if (rs < re) { pf0 = bsrc[rs]; pf1 = bsrc[rs + 1]; pf2 = bsrc[rs + 2]; pf3 = bsrc[rs + 3]; }
        }

        short8 o;
#pragma unroll
        for (int k = 0; k < 8; k++) o[k] = f2bf(ga[k]);
        if (active) *(short8*)(sp + r * HID) = o;
    }
}

// ---------------- gemm: Hout = act(S @ Wt2 + cnt-weighted bias) ----------------
// Round-5 skeleton with the gather replaced by deterministic streaming S loads:
// 9 K-chunks of 128; per chunk: B-frags (L2-hot) + LDS write of prefetched A regs +
// issue next chunk's A loads, ONE barrier, 16 MFMA. LDS dbuf race-free (adjacent
// chunks use different buffers; reuse separated by the intervening barrier).
// Wave shape 32Mx32N; C mapping: row = mt*16+lq*4+reg, col = n0+nt*16+lm (verified).

__global__ __launch_bounds__(256, 4) void gemm_kernel(const short* __restrict__ S,
                                                      const short* __restrict__ Wt2l,
                                                      const float* __restrict__ Bias, // [9][128]
                                                      const int* __restrict__ rowptr,
                                                      short* __restrict__ HoutBf,     // !last
                                                      float* __restrict__ HoutF,      // last
                                                      int last) {
    __shared__ short As[2][GM2 * FPITCH];         // 2 x 8704 B, [0] reused as Et
    __shared__ int   rp_s[NREL * (GM2 + 1)];      // 297 ints
    __shared__ float bias_s[NREL * HID];          // 4608 B

    int tid  = threadIdx.x;
    int wave = tid >> 6, lane = tid & 63;
    int lm = lane & 15, lq = lane >> 4;
    int row0 = blockIdx.x * GM2;
    int n0   = wave * 32;
    int grow = tid >> 3;                  // 0..31
    int gcc  = tid & 7;                   // 16-col group

    for (int i = tid; i < NREL * (GM2 + 1); i += 256) {
        int r = i / (GM2 + 1), o = i - r * (GM2 + 1);
        int d = row0 + o; if (d > NNODES) d = NNODES;
        rp_s[i] = rowptr[r * NNODES + d];
    }
    for (int i = tid; i < NREL * HID; i += 256) bias_s[i] = Bias[i];

    int ar = row0 + grow; if (ar > NNODES - 1) ar = NNODES - 1;
    const short* sb = S + (size_t)ar * KTOT + gcc * 16;

    // prefetch chunk 0
    short8 ra0 = *(const short8*)(sb);
    short8 ra1 = *(const short8*)(sb + 8);

    f32x4 acc[2][2];
#pragma unroll
    for (int a = 0; a < 2; a++)
#pragma unroll
        for (int b = 0; b < 2; b++) acc[a][b] = (f32x4){0.f, 0.f, 0.f, 0.f};

    const short* wb = Wt2l + (size_t)(n0 + lm) * KTOT + lq * 8;

    __syncthreads();   // rp_s/bias staged

    for (int kc = 0; kc < NREL; kc++) {           // 9 chunks of K=128
        short* Ap = &As[kc & 1][0];

        // B frags for this chunk (8 x 16 B, L2-hot)
        short8 bfr[2][4];
#pragma unroll
        for (int nt = 0; nt < 2; nt++)
#pragma unroll
            for (int ks = 0; ks < 4; ks++)
                bfr[nt][ks] = *(const short8*)(wb + (size_t)nt * 16 * KTOT + kc * HID + ks * 32);

        // commit prefetched A regs to LDS, then issue next chunk's loads
        short8* ap = (short8*)&Ap[grow * FPITCH + gcc * 16];
        ap[0] = ra0; ap[1] = ra1;
        if (kc + 1 < NREL) {
            ra0 = *(const short8*)(sb + (kc + 1) * HID);
            ra1 = *(const short8*)(sb + (kc + 1) * HID + 8);
        }
        __syncthreads();

#pragma unroll
        for (int ks = 0; ks < 4; ks++) {
            short8 af0 = *(const short8*)&Ap[(lm     ) * FPITCH + ks * 32 + lq * 8];
            short8 af1 = *(const short8*)&Ap[(lm + 16) * FPITCH + ks * 32 + lq * 8];
            __builtin_amdgcn_s_setprio(1);
            acc[0][0] = __builtin_amdgcn_mfma_f32_16x16x32_bf16(af0, bfr[0][ks], acc[0][0], 0, 0, 0);
            acc[1][0] = __builtin_amdgcn_mfma_f32_16x16x32_bf16(af1, bfr[0][ks], acc[1][0], 0, 0, 0);
            acc[0][1] = __builtin_amdgcn_mfma_f32_16x16x32_bf16(af0, bfr[1][ks], acc[0][1], 0, 0, 0);
            acc[1][1] = __builtin_amdgcn_mfma_f32_16x16x32_bf16(af1, bfr[1][ks], acc[1][1], 0, 0, 0);
            __builtin_amdgcn_s_setprio(0);
        }
    }
    __syncthreads();   // last MFMA read As[0] (kc=8); safe to reuse as Et

    // ---- epilogue: counts-weighted bias, activation, store ----
    if (!last) {
        short (*Et)[FPITCH] = (short(*)[FPITCH])&As[0][0];
#pragma unroll
        for (int mt = 0; mt < 2; mt++) {
#pragma unroll
            for (int reg = 0; reg < 4; reg++) {
                int rl = mt * 16 + lq * 4 + reg;
                float cr[NREL];
#pragma unroll
                for (int rr = 0; rr < NREL; rr++)
                    cr[rr] = (float)(rp_s[rr * (GM2 + 1) + rl + 1] - rp_s[rr * (GM2 + 1) + rl]);
#pragma unroll
                for (int nt = 0; nt < 2; nt++) {
                    int n = n0 + nt * 16 + lm;
                    float b = 0.f;
#pragma unroll
                    for (int rr = 0; rr < NREL; rr++) b += cr[rr] * bias_s[rr * HID + n];
                    float o = fmaxf(acc[mt][nt][reg] + b, 0.f);
                    Et[rl][n] = f2bf(o);
                }
            }
        }
        __syncthreads();
#pragma unroll
        for (int i = 0; i < 2; i++) {
            int p = i * 256 + tid;
            int row = p >> 4, cc = p & 15;
            int d = row0 + row;
            if (d < NNODES)
                *(short8*)(HoutBf + (size_t)d * HID + cc * 8) = *(const short8*)&Et[row][cc * 8];
        }
    } else {
#pragma unroll
        for (int mt = 0; mt < 2; mt++) {
#pragma unroll
            for (int reg = 0; reg < 4; reg++) {
                int rl = mt * 16 + lq * 4 + reg;
                int d  = row0 + rl;
                if (d >= NNODES) continue;
                float cr[NREL];
#pragma unroll
                for (int rr = 0; rr < NREL; rr++)
                    cr[rr] = (float)(rp_s[rr * (GM2 + 1) + rl + 1] - rp_s[rr * (GM2 + 1) + rl]);
#pragma unroll
                for (int nt = 0; nt < 2; nt++) {
                    int n = n0 + nt * 16 + lm;
                    float b = 0.f;
#pragma unroll
                    for (int rr = 0; rr < NREL; rr++) b += cr[rr] * bias_s[rr * HID + n];
                    HoutF[(size_t)d * HID + n] = acc[mt][nt][reg] + b;
                }
            }
        }
    }
}

// ---------------- driver ----------------

extern "C" void kernel_launch(void* const* d_in, const int* in_sizes, int n_in,
                              void* d_out, int out_size, void* d_ws, size_t ws_size,
                              hipStream_t stream) {
    const int*   edge_index = (const int*)d_in[0];   // [2, NEDGES]: row0=dest, row1=src
    const int*   etype      = (const int*)d_in[1];
    const float* emb        = (const float*)d_in[2];
    const float* W          = (const float*)d_in[3]; // [3,9,128,128]
    const float* Bias       = (const float*)d_in[4]; // [3,9,128]
    float*       out        = (float*)d_out;

    const int* dst  = edge_index;
    const int* srcA = edge_index + NEDGES;

    // ws layout (round-0 footprint, proven to fit: ~149 MB)
    short* Ebf  = (short*)d_ws;                             // 50000*128 bf16
    short* HbfA = Ebf  + (size_t)NNODES * HID;              // 50000*128 bf16 (single buffer: gemm never reads H)
    short* S    = HbfA + (size_t)NNODES * HID;              // 50000*1152 bf16 (115.2 MB)
    short* Wt2  = S + (size_t)NNODES * KTOT;                // 3*128*1152 bf16
    int*   bsrc     = (int*)(Wt2 + (size_t)NLAYERS * HID * KTOT);
    int*   bins     = bsrc + NEDGES + 8;                    // +8 pad (idx prefetch reads)
    int*   cursor   = bins + NBINS;
    int*   rowptr   = cursor + NBINS;                       // NBINS+1
    int*   blocksum = rowptr + NBINS + 1;
    int*   blockoff = blocksum + NBLK;

    hipMemsetAsync(bins, 0, NBINS * sizeof(int), stream);
    prep_kernel<<<HIST_BLKS + EMB_BLKS + W_BLKS, 256, 0, stream>>>(
        dst, etype, bins, emb, Ebf, W, Wt2);
    scan_pass1<<<NBLK, 256, 0, stream>>>(bins, blocksum);
    scan_pass2<<<1, 512, 0, stream>>>(blocksum, blockoff, rowptr);
    scan_pass3<<<NBLK, 256, 0, stream>>>(bins, blockoff, rowptr, cursor);
    place_kernel<<<(NEDGES + 255) / 256, 256, 0, stream>>>(dst, srcA, etype, cursor, bsrc);

    const int gemm_blocks = (NNODES + GM2 - 1) / GM2;   // 1563
    const short* Hin = Ebf;
    for (int l = 0; l < NLAYERS; l++) {
        int last = (l + 1 == NLAYERS);
        const short* Wtl = Wt2 + (size_t)l * HID * KTOT;
        const float* Bl  = Bias + (size_t)l * NREL * HID;
        gather_kernel<<<GTILES * GSLICES, 256, 0, stream>>>(Hin, rowptr, bsrc, S);
        gemm_kernel<<<gemm_blocks, 256, 0, stream>>>(S, Wtl, Bl, rowptr, HbfA, out, last);
        Hin = HbfA;   // gemm writes H for next layer; never reads it -> safe in-place cycle
    }
}